// Round 20
// baseline (194.654 us; speedup 1.0000x reference)
//
#include <hip/hip_runtime.h>
#include <hip/hip_bf16.h>

typedef unsigned short u16;
typedef unsigned int u32;
typedef __attribute__((ext_vector_type(4))) float f32x4;
typedef __attribute__((ext_vector_type(8))) __bf16 bf16x8;

#define B_   2
#define T_   2048
#define DM   2048
#define NH   16
#define NKV  4
#define HD   128

__device__ __forceinline__ u16 f2bf(float f){
    u32 u = __builtin_bit_cast(u32, f);
    u += 0x7FFFu + ((u >> 16) & 1u);
    return (u16)(u >> 16);
}
__device__ __forceinline__ float bf2f(u16 v){
    return __builtin_bit_cast(float, (u32)v << 16);
}

__device__ __forceinline__ float ex2(float x){
    float r; asm("v_exp_f32 %0, %1" : "=v"(r) : "v"(x)); return r;
}

__device__ __forceinline__ void gld_lds16(const void* g, void* l){
    __builtin_amdgcn_global_load_lds(
        (const __attribute__((address_space(1))) void*)g,
        (__attribute__((address_space(3))) void*)l, 16, 0, 0);
}

// ---------------- fused prep: cast x, transpose weights, rope table ----------------
__global__ void prep(const float* __restrict__ x,
                     const float* __restrict__ Wq, const float* __restrict__ Wk,
                     const float* __restrict__ Wv, const float* __restrict__ Wo,
                     u16* __restrict__ xb, u16* __restrict__ Wqkv, u16* __restrict__ Wot,
                     float2* __restrict__ tab){
    __shared__ float tile[32][33];
    int bid = blockIdx.x, tid = threadIdx.x;
    if (bid < 8192){
        int i = bid * 256 + tid;
        float4 v = ((const float4*)x)[i];
        ushort4 o;
        o.x = f2bf(v.x); o.y = f2bf(v.y); o.z = f2bf(v.z); o.w = f2bf(v.w);
        ((ushort4*)xb)[i] = o;
    } else if (bid < 18432){
        int tb = bid - 8192;
        int bx = tb % 160, byy = tb / 160;
        const float* W; u16* Out; int N; int nb; int perm;
        if (bx < 64)      { W = Wq; Out = Wqkv;                  N = 2048; nb = bx;      perm = 1; }
        else if (bx < 80) { W = Wk; Out = Wqkv + 2048ull * 2048; N = 512;  nb = bx - 64; perm = 1; }
        else if (bx < 96) { W = Wv; Out = Wqkv + 2560ull * 2048; N = 512;  nb = bx - 80; perm = 0; }
        else              { W = Wo; Out = Wot;                   N = 2048; nb = bx - 96; perm = 0; }
        int n0 = nb * 32, k0 = byy * 32;
        int tx = tid & 31, ty = tid >> 5;
#pragma unroll
        for (int i = 0; i < 4; i++)
            tile[ty + i * 8][tx] = W[(size_t)(k0 + ty + i * 8) * N + n0 + tx];
        __syncthreads();
#pragma unroll
        for (int i = 0; i < 4; i++){
            int n = n0 + ty + i * 8;
            int np = perm ? ((n & ~127) | ((n & 63) << 1) | ((n >> 6) & 1)) : n;
            Out[(size_t)np * 2048 + k0 + tx] = f2bf(tile[tx][ty + i * 8]);
        }
    } else {
        int idx = (bid - 18432) * 256 + tid;
        int i = idx & 63, t = idx >> 6;
        float ang = (float)t * exp2f((float)i * (-13.287712379549449f / 64.0f));
        float sv, cv;
        __sincosf(ang, &sv, &cv);
        tab[idx] = make_float2(cv, sv);
    }
}

#define BARR() asm volatile("s_barrier" ::: "memory")
#define VM0()  asm volatile("s_waitcnt vmcnt(0)" ::: "memory")
#define VM4()  asm volatile("s_waitcnt vmcnt(4)" ::: "memory")
#define VM8()  asm volatile("s_waitcnt vmcnt(8)" ::: "memory")
#define VM10() asm volatile("s_waitcnt vmcnt(10)" ::: "memory")

// ================= QKV GEMM: 128x192 tiles, 4-wave blocks, grid 512 (2 blocks/CU) =================
__global__ __launch_bounds__(256, 2) void gemm192h(const u16* __restrict__ A, const u16* __restrict__ Bt,
                                                   u16* __restrict__ Qp, u16* __restrict__ Ktl,
                                                   u16* __restrict__ Vtl, const float2* __restrict__ tab){
    __shared__ __attribute__((aligned(16))) u16 As[2][8192];    // 128 x 64
    __shared__ __attribute__((aligned(16))) u16 Bs[2][12288];   // 192 x 64
    const int tid = threadIdx.x;
    const int lane = tid & 63, w = tid >> 6;
    const int wm = w >> 1, wn = w & 1;
    const int tg = lane >> 4, lx = lane & 15;
    int swz = ((int)blockIdx.x & 7) * 64 + ((int)blockIdx.x >> 3);
    const int bx = swz & 15, by = swz >> 4;
    const int m0 = by * 128, n0 = bx * 192;
    const int K = 2048;
    const int kcx = (lane & 7) ^ ((lane >> 3) & 7);

    f32x4 acc[4][6];
    const f32x4 Z = {0.f, 0.f, 0.f, 0.f};
#pragma unroll
    for (int i = 0; i < 4; i++)
#pragma unroll
        for (int j = 0; j < 6; j++) acc[i][j] = Z;
    bf16x8 a_[4][2], b_[2][2];

    auto stA2 = [&](int buf, int h, int kt){
#pragma unroll
        for (int l = 0; l < 2; l++){
            int rb = h * 64 + w * 16 + l * 8;
            gld_lds16(A + (size_t)(m0 + rb + (lane >> 3)) * K + kt * 64 + kcx * 8,
                      &As[buf][rb * 64 + lane * 8]);
        }
    };
    auto stB2 = [&](int buf, int cp, int kt){
#pragma unroll
        for (int l = 0; l < 2; l++){
            int rb = l * 96 + cp * 32 + w * 8;
            gld_lds16(Bt + (size_t)(n0 + rb + (lane >> 3)) * K + kt * 64 + kcx * 8,
                      &Bs[buf][rb * 64 + lane * 8]);
        }
    };

#define RA192(BUF) { \
    const char* ab = (const char*)&As[BUF][0]; \
    _Pragma("unroll") for (int mi = 0; mi < 4; mi++){ \
        int rh = wm*64 + mi*16 + lx; \
        _Pragma("unroll") for (int ks = 0; ks < 2; ks++) \
            a_[mi][ks] = *(const bf16x8*)(ab + rh*128 + (((ks*4+tg)*16) ^ ((lx&7)<<4))); \
    } }
#define RB192(BUF, C) { \
    const char* bb = (const char*)&Bs[BUF][0]; \
    _Pragma("unroll") for (int n = 0; n < 2; n++){ \
        int rb = wn*96 + (C)*32 + n*16 + lx; \
        _Pragma("unroll") for (int ks = 0; ks < 2; ks++) \
            b_[n][ks] = *(const bf16x8*)(bb + rb*128 + (((ks*4+tg)*16) ^ ((lx&7)<<4))); \
    } }
#define MM192(C) { \
    __builtin_amdgcn_s_setprio(1); \
    _Pragma("unroll") for (int mi = 0; mi < 4; mi++) \
    _Pragma("unroll") for (int n = 0; n < 2; n++) \
    _Pragma("unroll") for (int ks = 0; ks < 2; ks++) \
        acc[mi][(C)*2+n] = __builtin_amdgcn_mfma_f32_16x16x32_bf16( \
            a_[mi][ks], b_[n][ks], acc[mi][(C)*2+n], 0, 0, 0); \
    __builtin_amdgcn_s_setprio(0); }

    stA2(0, 0, 0); stA2(0, 1, 0); stB2(0, 0, 0); stB2(0, 1, 0); stB2(0, 2, 0);
    stA2(1, 0, 1); stA2(1, 1, 1); stB2(1, 0, 1); stB2(1, 1, 1);
    VM8(); BARR();

#pragma unroll 1
    for (int it = 0; it < 16; it++){
        const int O  = 2*it + 1;
        const int E2 = (2*it + 2 < 32) ? 2*it + 2 : 31;
        const int O2 = (2*it + 3 < 32) ? 2*it + 3 : 31;
        RA192(0); RB192(0, 0); stB2(1, 2, O);
        BARR(); MM192(0); BARR();
        RB192(0, 1); stA2(0, 0, E2); stB2(0, 0, E2);
        BARR(); MM192(1); BARR();
        RB192(0, 2); stA2(0, 1, E2); stB2(0, 1, E2);
        BARR(); MM192(2); VM10(); BARR();
        RA192(1); RB192(1, 0); stB2(0, 2, E2);
        BARR(); MM192(0); BARR();
        RB192(1, 1); stA2(1, 0, O2); stB2(1, 0, O2);
        BARR(); MM192(1); BARR();
        RB192(1, 2); stA2(1, 1, O2); stB2(1, 1, O2);
        BARR(); MM192(2); VM10(); BARR();
    }

    const float QS = 0.08838834764831845f * 1.4426950408889634f;
#pragma unroll
    for (int mi = 0; mi < 4; mi++){
        int r0 = m0 + wm*64 + mi*16 + tg*4;
#pragma unroll
        for (int ci = 0; ci < 6; ci++){
            int cb = n0 + wn*96 + ci*16;
            int c  = cb + lx;
            if (cb < 2048){
                int ii = (c & 127) >> 1;
#pragma unroll
                for (int j = 0; j < 4; j++){
                    float v = acc[mi][ci][j];
                    float p = __shfl_xor(v, 1);
                    int t = (r0 + j) & 2047;
                    float2 cs = tab[t * 64 + ii];
                    float o = ((lx & 1) ? (v * cs.x + p * cs.y) : (v * cs.x - p * cs.y)) * QS;
                    Qp[(size_t)(r0 + j) * 2048 + c] = f2bf(o);
                }
            } else if (cb < 2560){
                int hk = (c >> 7) & 3;
                int dd = c & 127;
                int ii = dd >> 1;
#pragma unroll
                for (int j = 0; j < 4; j++){
                    int r = r0 + j;
                    int bb2 = r >> 11, tt = r & 2047;
                    float v = acc[mi][ci][j];
                    float p = __shfl_xor(v, 1);
                    float2 cs = tab[tt * 64 + ii];
                    float o = (lx & 1) ? (v * cs.x + p * cs.y) : (v * cs.x - p * cs.y);
                    size_t tb = ((size_t)(bb2 * 4 + hk) * 32 + (tt >> 6)) * 8192;
                    u32 byte = (u32)((tt & 63) * 256) + (((u32)(2 * dd)) ^ ((u32)((tt & 7) << 4)));
                    Ktl[tb + byte / 2] = f2bf(o);
                }
            } else {
                int bb2 = r0 >> 11, ss = r0 & 2047;
                int sb = ss & 63;
                int hk = (c >> 7) & 3;
                int d  = c & 127;
                size_t tb = ((size_t)(bb2 * 4 + hk) * 32 + (ss >> 6)) * 8192;
                u32 swzd = (u32)((d & 7) << 4);
#pragma unroll
                for (int j = 0; j < 4; j++){
                    int s = sb + j;
                    int slot = (s & 32) | (((s >> 2) & 3) << 3) | (((s >> 4) & 1) << 2) | (s & 3);
                    u32 byte = (u32)(d * 128) + (((u32)(2 * slot)) ^ swzd);
                    Vtl[tb + byte / 2] = f2bf(acc[mi][ci][j]);
                }
            }
        }
    }
}
#undef RA192
#undef RB192
#undef MM192

// ================= 256x256 8-phase GEMM (Wo split-K; R9 schedule) =================
#define READ_A(QA, BUF) { \
    const char* ab = (const char*)&As[BUF][wm][0]; \
    _Pragma("unroll") for (int i = 0; i < 4; i++){ \
        int rh = ((QA)*4 + i)*16 + lx; \
        _Pragma("unroll") for (int ks = 0; ks < 2; ks++) \
            a_[i][ks] = *(const bf16x8*)(ab + rh*128 + (((ks*4+tg)*16) ^ ((lx&7)<<4))); \
    } }
#define READ_B(QB, BUF) { \
    const char* bb = (const char*)&Bs[BUF][wn>>1][0]; \
    _Pragma("unroll") for (int n = 0; n < 2; n++){ \
        int rbh = (wn&1)*64 + ((QB)*2+n)*16 + lx; \
        _Pragma("unroll") for (int ks = 0; ks < 2; ks++) \
            b_[(QB)*2+n][ks] = *(const bf16x8*)(bb + rbh*128 + (((ks*4+tg)*16) ^ ((lx&7)<<4))); \
    } }
#define MFMA_Q(QA, QB) { \
    __builtin_amdgcn_s_setprio(1); \
    _Pragma("unroll") for (int i = 0; i < 4; i++) \
    _Pragma("unroll") for (int n = 0; n < 2; n++) \
    _Pragma("unroll") for (int ks = 0; ks < 2; ks++) \
        acc[(QA)*4+i][(QB)*2+n] = __builtin_amdgcn_mfma_f32_16x16x32_bf16( \
            a_[i][ks], b_[(QB)*2+n][ks], acc[(QA)*4+i][(QB)*2+n], 0, 0, 0); \
    __builtin_amdgcn_s_setprio(0); }

__global__ __launch_bounds__(512, 2) void gemmWo(const u16* __restrict__ A, const u16* __restrict__ Bt,
                                                 u16* __restrict__ O0){
    __shared__ __attribute__((aligned(16))) u16 As[2][2][8192];
    __shared__ __attribute__((aligned(16))) u16 Bs[2][2][8192];
    const int tid = threadIdx.x;
    const int lane = tid & 63, w = tid >> 6;
    const int wm = w >> 2, wn = w & 3;
    const int tg = lane >> 4, lx = lane & 15;
    int q8 = (int)gridDim.x >> 3;
    int swz = ((int)blockIdx.x & 7) * q8 + ((int)blockIdx.x >> 3);
    int kh = swz >> 7; swz &= 127;
    const int bx = swz & 7, by = swz >> 3;
    const int m0 = by * 256, n0 = bx * 256;
    const int K = 2048;
    const int NIT = 8;
    const int kt0 = kh * 16;
    const int ltMax = 2 * NIT - 1;
    const int kcx = (lane & 7) ^ ((lane >> 3) & 7);

    f32x4 acc[8][4];
    const f32x4 Z = {0.f, 0.f, 0.f, 0.f};
#pragma unroll
    for (int i = 0; i < 8; i++)
#pragma unroll
        for (int j = 0; j < 4; j++) acc[i][j] = Z;
    bf16x8 a_[4][2], b_[4][2];

    auto stA = [&](int buf, int q, int kt){
        int mh = w >> 2;
        int s0 = (w & 3) * 2;
#pragma unroll
        for (int l = 0; l < 2; l++){
            int s = s0 + l;
            gld_lds16(A + (size_t)(m0 + mh*128 + q*64 + s*8 + (lane>>3)) * K + kt*64 + kcx*8,
                      &As[buf][mh][q*4096 + s*512 + lane*8]);
        }
    };
    auto stB = [&](int buf, int q, int kt){
        int bh = w >> 2;
        int hi = (w >> 1) & 1;
        int s0 = (w & 1) * 2;
#pragma unroll
        for (int l = 0; l < 2; l++){
            int s = s0 + l;
            gld_lds16(Bt + (size_t)(n0 + bh*128 + hi*64 + q*32 + s*8 + (lane>>3)) * K + kt*64 + kcx*8,
                      &Bs[buf][bh][hi*4096 + q*2048 + s*512 + lane*8]);
        }
    };

    stA(0, 0, kt0); stB(0, 0, kt0); stA(0, 1, kt0); stB(0, 1, kt0);
    stA(1, 0, kt0 + 1); stB(1, 0, kt0 + 1);
    VM4(); BARR();

#pragma unroll 1
    for (int it = 0; it < NIT; it++){
        const int T1 = kt0 + 2*it + 1;
        const int T2 = kt0 + ((2*it + 2 < ltMax) ? 2*it + 2 : ltMax);
        const int T3 = kt0 + ((2*it + 3 < ltMax) ? 2*it + 3 : ltMax);
        READ_A(0, 0); READ_B(0, 0); stA(1, 1, T1);
        BARR(); MFMA_Q(0, 0); BARR();
        READ_B(1, 0); stB(1, 1, T1);
        BARR(); MFMA_Q(0, 1); BARR();
        READ_A(1, 0); stA(0, 0, T2);
        BARR(); MFMA_Q(1, 0); BARR();
        stB(0, 0, T2);
        BARR(); MFMA_Q(1, 1); VM4(); BARR();
        READ_A(0, 1); READ_B(0, 1); stA(0, 1, T2);
        BARR(); MFMA_Q(0, 0); BARR();
        READ_B(1, 1); stB(0, 1, T2);
        BARR(); MFMA_Q(0, 1); BARR();
        READ_A(1, 1); stA(1, 0, T3);
        BARR(); MFMA_Q(1, 0); BARR();
        stB(1, 0, T3);
        BARR(); MFMA_Q(1, 1); VM4(); BARR();
    }

    u16* C = O0 + (size_t)kh * 4096 * 2048;
#pragma unroll
    for (int mi = 0; mi < 8; mi++)
#pragma unroll
        for (int ni = 0; ni < 4; ni++){
            int r0 = m0 + wm*128 + mi*16 + tg*4;
            int c  = n0 + wn*64 + ni*16 + lx;
#pragma unroll
            for (int j = 0; j < 4; j++)
                C[(size_t)(r0 + j) * 2048 + c] = f2bf(acc[mi][ni][j]);
        }
}

// ---------------- split-K reduce ----------------
__global__ void reduceWo(const u16* __restrict__ P, float* __restrict__ out){
    size_t t = (size_t)blockIdx.x * 256 + threadIdx.x;
    const u16* p0 = P + t * 8;
    const u16* p1 = P + 4096ull * 2048 + t * 8;
    uint4 a = *(const uint4*)p0;
    uint4 b = *(const uint4*)p1;
    const u16* as = (const u16*)&a;
    const u16* bs = (const u16*)&b;
    float4 o0, o1;
    o0.x = bf2f(as[0]) + bf2f(bs[0]); o0.y = bf2f(as[1]) + bf2f(bs[1]);
    o0.z = bf2f(as[2]) + bf2f(bs[2]); o0.w = bf2f(as[3]) + bf2f(bs[3]);
    o1.x = bf2f(as[4]) + bf2f(bs[4]); o1.y = bf2f(as[5]) + bf2f(bs[5]);
    o1.z = bf2f(as[6]) + bf2f(bs[6]); o1.w = bf2f(as[7]) + bf2f(bs[7]);
    ((float4*)out)[t * 2]     = o0;
    ((float4*)out)[t * 2 + 1] = o1;
}

// ---------------- causal GQA flash attention: swapped QK^T + att[2] pipeline ----------------
// Body i computes QK(i) INTERLEAVED with softmax(i-1) (independent reg sets saA/saB,
// statically named via 2-unrolled pairing), then PV(i-1). Single K/V LDS buffers
// (32 KB, 4 blocks/CU). vmcnt audit: entry VM4 retires stK(i) (keeps stV(i-1));
// mid VM4 retires stV(i-1) (keeps stK(i+1)); VM0 when no stK issued. Masking only
// in the tail body (scores of iter n-1).
__global__ __launch_bounds__(256) void attn11(const u16* __restrict__ Q, const u16* __restrict__ Kt,
                                              const u16* __restrict__ Vt, u16* __restrict__ Y){
    __shared__ __attribute__((aligned(16))) u16 Ks[8192];
    __shared__ __attribute__((aligned(16))) u16 Vs[8192];
    const int tid = threadIdx.x;
    const int lane = tid & 63, w = tid >> 6;
    const int tg = lane >> 4, lx = lane & 15;
    int gid = blockIdx.x;
    int z = gid & 255, k4 = gid >> 8;
    int j8 = z & 7, h = (z >> 3) & 15, b = z >> 7;
    int qt = (k4 == 0) ? j8 : (k4 == 1) ? 31 - j8 : (k4 == 2) ? j8 + 8 : 23 - j8;
    const int hkv = h >> 2;
    const size_t kvBase = ((size_t)(b * NKV + hkv) * 32) * 8192;
    const f32x4 Z = {0.f, 0.f, 0.f, 0.f};

    auto STAGE_K = [&](int it){
        const u16* kg = Kt + kvBase + (size_t)it * 8192;
#pragma unroll
        for (int i = 0; i < 4; i++){
            int is = w * 4 + i;
            gld_lds16(kg + is * 512 + lane * 8, &Ks[is * 512]);
        }
    };
    auto STAGE_V = [&](int it){
        const u16* vg = Vt + kvBase + (size_t)it * 8192;
#pragma unroll
        for (int i = 0; i < 4; i++){
            int is = w * 4 + i;
            gld_lds16(vg + is * 512 + lane * 8, &Vs[is * 512]);
        }
    };

    const int q0 = qt * 64;
    const int qrow = q0 + w * 16 + lx;
    bf16x8 qfr[4];
#pragma unroll
    for (int kk = 0; kk < 4; kk++)
        qfr[kk] = *(const bf16x8*)(Q + (size_t)(b * T_ + qrow) * DM + h * HD + kk * 32 + tg * 8);
    f32x4 accO[8];
#pragma unroll
    for (int i = 0; i < 8; i++) accO[i] = Z;
    float mr = -INFINITY;
    float lp = 0.f;
    const int n = qt + 1;

    f32x4 saA[4], saB[4];
    bf16x8 pa0, pa1;

#define QK16(SA) { \
    _Pragma("unroll") for (int c = 0; c < 4; c++) SA[c] = Z; \
    _Pragma("unroll") for (int c = 0; c < 4; c++){ \
        int s = c * 16 + lx; \
        u32 kswz = (u32)((s & 7) << 4); \
        const char* kb = (const char*)&Ks[0] + s * 256; \
        _Pragma("unroll") for (int kk = 0; kk < 4; kk++){ \
            bf16x8 kf = *(const bf16x8*)(kb + (((u32)(kk * 64 + tg * 16)) ^ kswz)); \
            SA[c] = __builtin_amdgcn_mfma_f32_16x16x32_bf16(kf, qfr[kk], SA[c], 0, 0, 0); \
        } } }

#define SM16(SP, MASKED, LI) { \
    float tl = -INFINITY; \
    _Pragma("unroll") for (int c = 0; c < 4; c++) \
    _Pragma("unroll") for (int j = 0; j < 4; j++){ \
        float a = SP[c][j]; \
        if (MASKED){ if ((LI) * 64 + tg * 4 + c * 16 + j > qrow) a = -INFINITY; } \
        SP[c][j] = a; \
        tl = fmaxf(tl, a); } \
    if (!__all(tl <= mr + 8.f)){ \
        float t = fmaxf(tl, __shfl_xor(tl, 16)); \
        t = fmaxf(t, __shfl_xor(t, 32)); \
        float mn = fmaxf(mr, t); \
        float corrq = ex2(mr - mn); \
        mr = mn; lp *= corrq; \
        float corrO[4]; \
        _Pragma("unroll") for (int j = 0; j < 4; j++) \
            corrO[j] = __shfl(corrq, (lane & 48) + ((lane >> 4) << 2) + j); \
        _Pragma("unroll") for (int dt = 0; dt < 8; dt++){ \
            f32x4 t2 = accO[dt]; \
            t2[0] *= corrO[0]; t2[1] *= corrO[1]; t2[2] *= corrO[2]; t2[3] *= corrO[3]; \
            accO[dt] = t2; } } \
    { float pp[4][4]; \
      _Pragma("unroll") for (int c = 0; c < 4; c++) \
      _Pragma("unroll") for (int j = 0; j < 4; j++){ \
          float v = ex2(SP[c][j] - mr); pp[c][j] = v; lp += v; } \
      u32 w0, w1, w2, w3; \
      asm("v_cvt_pk_bf16_f32 %0, %1, %2" : "=v"(w0) : "v"(pp[0][0]), "v"(pp[0][1])); \
      asm("v_cvt_pk_bf16_f32 %0, %1, %2" : "=v"(w1) : "v"(pp[0][2]), "v"(pp[0][3])); \
      asm("v_cvt_pk_bf16_f32 %0, %1, %2" : "=v"(w2) : "v"(pp[1][0]), "v"(pp[1][1])); \
      asm("v_cvt_pk_bf16_f32 %0, %1, %2" : "=v"(w3) : "v"(pp[1][2]), "v"(pp[1][3])); \
      u32 r1[4] = {w0, w1, w2, w3}; \
      pa0 = __builtin_bit_cast(bf16x8, *(uint4*)r1); \
      asm("v_cvt_pk_bf16_f32 %0, %1, %2" : "=v"(w0) : "v"(pp[2][0]), "v"(pp[2][1])); \
      asm("v_cvt_pk_bf16_f32 %0, %1, %2" : "=v"(w1) : "v"(pp[2][2]), "v"(pp[2][3])); \
      asm("v_cvt_pk_bf16_f32 %0, %1, %2" : "=v"(w2) : "v"(pp[3][0]), "v"(pp[3][1])); \
      asm("v_cvt_pk_bf16_f32 %0, %1, %2" : "=v"(w3) : "v"(pp[3][2]), "v"(pp[3][3])); \
      u32 r2[4] = {w0, w1, w2, w3}; \
      pa1 = __builtin_bit_cast(bf16x8, *(uint4*)r2); } }

#define PV16() { \
    _Pragma("unroll") for (int dt = 0; dt < 8; dt++){ \
        int d = dt * 16 + lx; \
        u32 vswz = (u32)((d & 7) << 4); \
        const char* vb = (const char*)&Vs[0] + d * 128; \
        bf16x8 vf0 = *(const bf16x8*)(vb + (((u32)(tg * 16))      ^ vswz)); \
        bf16x8 vf1 = *(const bf16x8*)(vb + (((u32)(tg * 16 + 64)) ^ vswz)); \
        accO[dt] = __builtin_amdgcn_mfma_f32_16x16x32_bf16(pa0, vf0, accO[dt], 0, 0, 0); \
        accO[dt] = __builtin_amdgcn_mfma_f32_16x16x32_bf16(pa1, vf1, accO[dt], 0, 0, 0); } }

#define AFULL(SC, SP, I) { \
    VM4(); BARR(); \
    __builtin_amdgcn_s_setprio(1); \
    QK16(SC); \
    SM16(SP, false, 0); \
    __builtin_amdgcn_s_setprio(0); \
    BARR(); \
    if ((I) + 1 < n){ STAGE_K((I) + 1); VM4(); } else { VM0(); } \
    BARR(); \
    __builtin_amdgcn_s_setprio(1); \
    PV16(); \
    __builtin_amdgcn_s_setprio(0); \
    BARR(); \
    STAGE_V(I); }

#define ATAIL(SP, LI) { \
    VM0(); BARR(); \
    SM16(SP, true, LI); \
    __builtin_amdgcn_s_setprio(1); \
    PV16(); \
    __builtin_amdgcn_s_setprio(0); }

    // prologue + body 0 (QK(0) only)
    STAGE_K(0);
    VM0(); BARR();
    __builtin_amdgcn_s_setprio(1);
    QK16(saA);
    __builtin_amdgcn_s_setprio(0);
    BARR();
    if (n > 1) STAGE_K(1);
    STAGE_V(0);

    int i = 1;
#pragma unroll 1
    for (; i + 1 < n; i += 2){
        AFULL(saB, saA, i);
        AFULL(saA, saB, i + 1);
    }
    if (i < n){
        AFULL(saB, saA, i);
        ATAIL(saB, n - 1);
    } else {
        ATAIL(saA, n - 1);
    }

#undef QK16
#undef SM16
#undef PV16
#undef AFULL
#undef ATAIL

    lp += __shfl_xor(lp, 16);
    lp += __shfl_xor(lp, 32);
    float invq = 1.0f / lp;
    float inv[4];
#pragma unroll
    for (int j = 0; j < 4; j++)
        inv[j] = __shfl(invq, (lane & 48) + ((lane >> 4) << 2) + j);
#pragma unroll
    for (int dt = 0; dt < 8; dt++)
#pragma unroll
        for (int j = 0; j < 4; j++){
            int qr = q0 + w * 16 + tg * 4 + j;
            int d = dt * 16 + lx;
            Y[(size_t)(b * T_ + qr) * DM + h * HD + d] = f2bf(accO[dt][j] * inv[j]);
        }
}

extern "C" void kernel_launch(void* const* d_in, const int* in_sizes, int n_in,
                              void* d_out, int out_size, void* d_ws, size_t ws_size,
                              hipStream_t stream){
    const float* x  = (const float*)d_in[0];
    const float* Wq = (const float*)d_in[1];
    const float* Wk = (const float*)d_in[2];
    const float* Wv = (const float*)d_in[3];
    const float* Wo = (const float*)d_in[4];

    char* ws = (char*)d_ws;
    size_t off = 0;
    auto alloc = [&](size_t bytes){ void* p = ws + off; off += (bytes + 255) & ~255ull; return p; };
    u16*    xb   = (u16*)alloc(4096ull * 2048 * 2);
    u16*    Wqkv = (u16*)alloc(3072ull * 2048 * 2);
    u16*    Wot  = (u16*)alloc(2048ull * 2048 * 2);
    u16*    qbb  = (u16*)alloc(4096ull * 2048 * 2);
    u16*    ktl  = (u16*)alloc(2ull * 4 * 32 * 8192 * 2);
    u16*    vtl  = (u16*)alloc(2ull * 4 * 32 * 8192 * 2);
    u16*    ybb  = (u16*)alloc(4096ull * 2048 * 2);
    u16*    pbb  = (u16*)alloc(2ull * 4096 * 2048 * 2);
    float2* tab  = (float2*)alloc(2048ull * 64 * 8);

    prep<<<18944, 256, 0, stream>>>(x, Wq, Wk, Wv, Wo, xb, Wqkv, Wot, tab);

    gemm192h<<<512, 256, 0, stream>>>(xb, Wqkv, qbb, ktl, vtl, tab);

    attn11<<<1024, 256, 0, stream>>>(qbb, ktl, vtl, ybb);

    gemmWo<<<256, 512, 0, stream>>>(ybb, Wot, pbb);
    reduceWo<<<4096, 256, 0, stream>>>(pbb, (float*)d_out);
}

// Round 21
// 183.687 us; speedup vs baseline: 1.0597x; 1.0597x over previous
//
#include <hip/hip_runtime.h>
#include <hip/hip_bf16.h>

typedef unsigned short u16;
typedef unsigned int u32;
typedef __attribute__((ext_vector_type(4))) float f32x4;
typedef __attribute__((ext_vector_type(8))) __bf16 bf16x8;

#define B_   2
#define T_   2048
#define DM   2048
#define NH   16
#define NKV  4
#define HD   128

__device__ __forceinline__ u16 f2bf(float f){
    u32 u = __builtin_bit_cast(u32, f);
    u += 0x7FFFu + ((u >> 16) & 1u);
    return (u16)(u >> 16);
}
__device__ __forceinline__ float bf2f(u16 v){
    return __builtin_bit_cast(float, (u32)v << 16);
}

__device__ __forceinline__ float ex2(float x){
    float r; asm("v_exp_f32 %0, %1" : "=v"(r) : "v"(x)); return r;
}

__device__ __forceinline__ void gld_lds16(const void* g, void* l){
    __builtin_amdgcn_global_load_lds(
        (const __attribute__((address_space(1))) void*)g,
        (__attribute__((address_space(3))) void*)l, 16, 0, 0);
}

// ---------------- fused prep: cast x, transpose weights, rope table ----------------
__global__ void prep(const float* __restrict__ x,
                     const float* __restrict__ Wq, const float* __restrict__ Wk,
                     const float* __restrict__ Wv, const float* __restrict__ Wo,
                     u16* __restrict__ xb, u16* __restrict__ Wqkv, u16* __restrict__ Wot,
                     float2* __restrict__ tab){
    __shared__ float tile[32][33];
    int bid = blockIdx.x, tid = threadIdx.x;
    if (bid < 8192){
        int i = bid * 256 + tid;
        float4 v = ((const float4*)x)[i];
        ushort4 o;
        o.x = f2bf(v.x); o.y = f2bf(v.y); o.z = f2bf(v.z); o.w = f2bf(v.w);
        ((ushort4*)xb)[i] = o;
    } else if (bid < 18432){
        int tb = bid - 8192;
        int bx = tb % 160, byy = tb / 160;
        const float* W; u16* Out; int N; int nb; int perm;
        if (bx < 64)      { W = Wq; Out = Wqkv;                  N = 2048; nb = bx;      perm = 1; }
        else if (bx < 80) { W = Wk; Out = Wqkv + 2048ull * 2048; N = 512;  nb = bx - 64; perm = 1; }
        else if (bx < 96) { W = Wv; Out = Wqkv + 2560ull * 2048; N = 512;  nb = bx - 80; perm = 0; }
        else              { W = Wo; Out = Wot;                   N = 2048; nb = bx - 96; perm = 0; }
        int n0 = nb * 32, k0 = byy * 32;
        int tx = tid & 31, ty = tid >> 5;
#pragma unroll
        for (int i = 0; i < 4; i++)
            tile[ty + i * 8][tx] = W[(size_t)(k0 + ty + i * 8) * N + n0 + tx];
        __syncthreads();
#pragma unroll
        for (int i = 0; i < 4; i++){
            int n = n0 + ty + i * 8;
            int np = perm ? ((n & ~127) | ((n & 63) << 1) | ((n >> 6) & 1)) : n;
            Out[(size_t)np * 2048 + k0 + tx] = f2bf(tile[tx][ty + i * 8]);
        }
    } else {
        int idx = (bid - 18432) * 256 + tid;
        int i = idx & 63, t = idx >> 6;
        float ang = (float)t * exp2f((float)i * (-13.287712379549449f / 64.0f));
        float sv, cv;
        __sincosf(ang, &sv, &cv);
        tab[idx] = make_float2(cv, sv);
    }
}

#define BARR() asm volatile("s_barrier" ::: "memory")
#define VM0()  asm volatile("s_waitcnt vmcnt(0)" ::: "memory")
#define VM4()  asm volatile("s_waitcnt vmcnt(4)" ::: "memory")
#define VM8()  asm volatile("s_waitcnt vmcnt(8)" ::: "memory")
#define VM10() asm volatile("s_waitcnt vmcnt(10)" ::: "memory")

// ================= QKV GEMM: 128x192 tiles, 4-wave blocks, grid 512 (2 blocks/CU) =================
__global__ __launch_bounds__(256, 2) void gemm192h(const u16* __restrict__ A, const u16* __restrict__ Bt,
                                                   u16* __restrict__ Qp, u16* __restrict__ Ktl,
                                                   u16* __restrict__ Vtl, const float2* __restrict__ tab){
    __shared__ __attribute__((aligned(16))) u16 As[2][8192];    // 128 x 64
    __shared__ __attribute__((aligned(16))) u16 Bs[2][12288];   // 192 x 64
    const int tid = threadIdx.x;
    const int lane = tid & 63, w = tid >> 6;
    const int wm = w >> 1, wn = w & 1;
    const int tg = lane >> 4, lx = lane & 15;
    int swz = ((int)blockIdx.x & 7) * 64 + ((int)blockIdx.x >> 3);
    const int bx = swz & 15, by = swz >> 4;
    const int m0 = by * 128, n0 = bx * 192;
    const int K = 2048;
    const int kcx = (lane & 7) ^ ((lane >> 3) & 7);

    f32x4 acc[4][6];
    const f32x4 Z = {0.f, 0.f, 0.f, 0.f};
#pragma unroll
    for (int i = 0; i < 4; i++)
#pragma unroll
        for (int j = 0; j < 6; j++) acc[i][j] = Z;
    bf16x8 a_[4][2], b_[2][2];

    auto stA2 = [&](int buf, int h, int kt){
#pragma unroll
        for (int l = 0; l < 2; l++){
            int rb = h * 64 + w * 16 + l * 8;
            gld_lds16(A + (size_t)(m0 + rb + (lane >> 3)) * K + kt * 64 + kcx * 8,
                      &As[buf][rb * 64 + lane * 8]);
        }
    };
    auto stB2 = [&](int buf, int cp, int kt){
#pragma unroll
        for (int l = 0; l < 2; l++){
            int rb = l * 96 + cp * 32 + w * 8;
            gld_lds16(Bt + (size_t)(n0 + rb + (lane >> 3)) * K + kt * 64 + kcx * 8,
                      &Bs[buf][rb * 64 + lane * 8]);
        }
    };

#define RA192(BUF) { \
    const char* ab = (const char*)&As[BUF][0]; \
    _Pragma("unroll") for (int mi = 0; mi < 4; mi++){ \
        int rh = wm*64 + mi*16 + lx; \
        _Pragma("unroll") for (int ks = 0; ks < 2; ks++) \
            a_[mi][ks] = *(const bf16x8*)(ab + rh*128 + (((ks*4+tg)*16) ^ ((lx&7)<<4))); \
    } }
#define RB192(BUF, C) { \
    const char* bb = (const char*)&Bs[BUF][0]; \
    _Pragma("unroll") for (int n = 0; n < 2; n++){ \
        int rb = wn*96 + (C)*32 + n*16 + lx; \
        _Pragma("unroll") for (int ks = 0; ks < 2; ks++) \
            b_[n][ks] = *(const bf16x8*)(bb + rb*128 + (((ks*4+tg)*16) ^ ((lx&7)<<4))); \
    } }
#define MM192(C) { \
    __builtin_amdgcn_s_setprio(1); \
    _Pragma("unroll") for (int mi = 0; mi < 4; mi++) \
    _Pragma("unroll") for (int n = 0; n < 2; n++) \
    _Pragma("unroll") for (int ks = 0; ks < 2; ks++) \
        acc[mi][(C)*2+n] = __builtin_amdgcn_mfma_f32_16x16x32_bf16( \
            a_[mi][ks], b_[n][ks], acc[mi][(C)*2+n], 0, 0, 0); \
    __builtin_amdgcn_s_setprio(0); }

    stA2(0, 0, 0); stA2(0, 1, 0); stB2(0, 0, 0); stB2(0, 1, 0); stB2(0, 2, 0);
    stA2(1, 0, 1); stA2(1, 1, 1); stB2(1, 0, 1); stB2(1, 1, 1);
    VM8(); BARR();

#pragma unroll 1
    for (int it = 0; it < 16; it++){
        const int O  = 2*it + 1;
        const int E2 = (2*it + 2 < 32) ? 2*it + 2 : 31;
        const int O2 = (2*it + 3 < 32) ? 2*it + 3 : 31;
        RA192(0); RB192(0, 0); stB2(1, 2, O);
        BARR(); MM192(0); BARR();
        RB192(0, 1); stA2(0, 0, E2); stB2(0, 0, E2);
        BARR(); MM192(1); BARR();
        RB192(0, 2); stA2(0, 1, E2); stB2(0, 1, E2);
        BARR(); MM192(2); VM10(); BARR();
        RA192(1); RB192(1, 0); stB2(0, 2, E2);
        BARR(); MM192(0); BARR();
        RB192(1, 1); stA2(1, 0, O2); stB2(1, 0, O2);
        BARR(); MM192(1); BARR();
        RB192(1, 2); stA2(1, 1, O2); stB2(1, 1, O2);
        BARR(); MM192(2); VM10(); BARR();
    }

    const float QS = 0.08838834764831845f * 1.4426950408889634f;
#pragma unroll
    for (int mi = 0; mi < 4; mi++){
        int r0 = m0 + wm*64 + mi*16 + tg*4;
#pragma unroll
        for (int ci = 0; ci < 6; ci++){
            int cb = n0 + wn*96 + ci*16;
            int c  = cb + lx;
            if (cb < 2048){
                int ii = (c & 127) >> 1;
#pragma unroll
                for (int j = 0; j < 4; j++){
                    float v = acc[mi][ci][j];
                    float p = __shfl_xor(v, 1);
                    int t = (r0 + j) & 2047;
                    float2 cs = tab[t * 64 + ii];
                    float o = ((lx & 1) ? (v * cs.x + p * cs.y) : (v * cs.x - p * cs.y)) * QS;
                    Qp[(size_t)(r0 + j) * 2048 + c] = f2bf(o);
                }
            } else if (cb < 2560){
                int hk = (c >> 7) & 3;
                int dd = c & 127;
                int ii = dd >> 1;
#pragma unroll
                for (int j = 0; j < 4; j++){
                    int r = r0 + j;
                    int bb2 = r >> 11, tt = r & 2047;
                    float v = acc[mi][ci][j];
                    float p = __shfl_xor(v, 1);
                    float2 cs = tab[tt * 64 + ii];
                    float o = (lx & 1) ? (v * cs.x + p * cs.y) : (v * cs.x - p * cs.y);
                    size_t tb = ((size_t)(bb2 * 4 + hk) * 32 + (tt >> 6)) * 8192;
                    u32 byte = (u32)((tt & 63) * 256) + (((u32)(2 * dd)) ^ ((u32)((tt & 7) << 4)));
                    Ktl[tb + byte / 2] = f2bf(o);
                }
            } else {
                int bb2 = r0 >> 11, ss = r0 & 2047;
                int sb = ss & 63;
                int hk = (c >> 7) & 3;
                int d  = c & 127;
                size_t tb = ((size_t)(bb2 * 4 + hk) * 32 + (ss >> 6)) * 8192;
                u32 swzd = (u32)((d & 7) << 4);
#pragma unroll
                for (int j = 0; j < 4; j++){
                    int s = sb + j;
                    int slot = (s & 32) | (((s >> 2) & 3) << 3) | (((s >> 4) & 1) << 2) | (s & 3);
                    u32 byte = (u32)(d * 128) + (((u32)(2 * slot)) ^ swzd);
                    Vtl[tb + byte / 2] = f2bf(acc[mi][ci][j]);
                }
            }
        }
    }
}
#undef RA192
#undef RB192
#undef MM192

// ================= 256x256 8-phase GEMM (Wo split-K; R9 schedule) =================
#define READ_A(QA, BUF) { \
    const char* ab = (const char*)&As[BUF][wm][0]; \
    _Pragma("unroll") for (int i = 0; i < 4; i++){ \
        int rh = ((QA)*4 + i)*16 + lx; \
        _Pragma("unroll") for (int ks = 0; ks < 2; ks++) \
            a_[i][ks] = *(const bf16x8*)(ab + rh*128 + (((ks*4+tg)*16) ^ ((lx&7)<<4))); \
    } }
#define READ_B(QB, BUF) { \
    const char* bb = (const char*)&Bs[BUF][wn>>1][0]; \
    _Pragma("unroll") for (int n = 0; n < 2; n++){ \
        int rbh = (wn&1)*64 + ((QB)*2+n)*16 + lx; \
        _Pragma("unroll") for (int ks = 0; ks < 2; ks++) \
            b_[(QB)*2+n][ks] = *(const bf16x8*)(bb + rbh*128 + (((ks*4+tg)*16) ^ ((lx&7)<<4))); \
    } }
#define MFMA_Q(QA, QB) { \
    __builtin_amdgcn_s_setprio(1); \
    _Pragma("unroll") for (int i = 0; i < 4; i++) \
    _Pragma("unroll") for (int n = 0; n < 2; n++) \
    _Pragma("unroll") for (int ks = 0; ks < 2; ks++) \
        acc[(QA)*4+i][(QB)*2+n] = __builtin_amdgcn_mfma_f32_16x16x32_bf16( \
            a_[i][ks], b_[(QB)*2+n][ks], acc[(QA)*4+i][(QB)*2+n], 0, 0, 0); \
    __builtin_amdgcn_s_setprio(0); }

__global__ __launch_bounds__(512, 2) void gemmWo(const u16* __restrict__ A, const u16* __restrict__ Bt,
                                                 u16* __restrict__ O0){
    __shared__ __attribute__((aligned(16))) u16 As[2][2][8192];
    __shared__ __attribute__((aligned(16))) u16 Bs[2][2][8192];
    const int tid = threadIdx.x;
    const int lane = tid & 63, w = tid >> 6;
    const int wm = w >> 2, wn = w & 3;
    const int tg = lane >> 4, lx = lane & 15;
    int q8 = (int)gridDim.x >> 3;
    int swz = ((int)blockIdx.x & 7) * q8 + ((int)blockIdx.x >> 3);
    int kh = swz >> 7; swz &= 127;
    const int bx = swz & 7, by = swz >> 3;
    const int m0 = by * 256, n0 = bx * 256;
    const int K = 2048;
    const int NIT = 8;
    const int kt0 = kh * 16;
    const int ltMax = 2 * NIT - 1;
    const int kcx = (lane & 7) ^ ((lane >> 3) & 7);

    f32x4 acc[8][4];
    const f32x4 Z = {0.f, 0.f, 0.f, 0.f};
#pragma unroll
    for (int i = 0; i < 8; i++)
#pragma unroll
        for (int j = 0; j < 4; j++) acc[i][j] = Z;
    bf16x8 a_[4][2], b_[4][2];

    auto stA = [&](int buf, int q, int kt){
        int mh = w >> 2;
        int s0 = (w & 3) * 2;
#pragma unroll
        for (int l = 0; l < 2; l++){
            int s = s0 + l;
            gld_lds16(A + (size_t)(m0 + mh*128 + q*64 + s*8 + (lane>>3)) * K + kt*64 + kcx*8,
                      &As[buf][mh][q*4096 + s*512 + lane*8]);
        }
    };
    auto stB = [&](int buf, int q, int kt){
        int bh = w >> 2;
        int hi = (w >> 1) & 1;
        int s0 = (w & 1) * 2;
#pragma unroll
        for (int l = 0; l < 2; l++){
            int s = s0 + l;
            gld_lds16(Bt + (size_t)(n0 + bh*128 + hi*64 + q*32 + s*8 + (lane>>3)) * K + kt*64 + kcx*8,
                      &Bs[buf][bh][hi*4096 + q*2048 + s*512 + lane*8]);
        }
    };

    stA(0, 0, kt0); stB(0, 0, kt0); stA(0, 1, kt0); stB(0, 1, kt0);
    stA(1, 0, kt0 + 1); stB(1, 0, kt0 + 1);
    VM4(); BARR();

#pragma unroll 1
    for (int it = 0; it < NIT; it++){
        const int T1 = kt0 + 2*it + 1;
        const int T2 = kt0 + ((2*it + 2 < ltMax) ? 2*it + 2 : ltMax);
        const int T3 = kt0 + ((2*it + 3 < ltMax) ? 2*it + 3 : ltMax);
        READ_A(0, 0); READ_B(0, 0); stA(1, 1, T1);
        BARR(); MFMA_Q(0, 0); BARR();
        READ_B(1, 0); stB(1, 1, T1);
        BARR(); MFMA_Q(0, 1); BARR();
        READ_A(1, 0); stA(0, 0, T2);
        BARR(); MFMA_Q(1, 0); BARR();
        stB(0, 0, T2);
        BARR(); MFMA_Q(1, 1); VM4(); BARR();
        READ_A(0, 1); READ_B(0, 1); stA(0, 1, T2);
        BARR(); MFMA_Q(0, 0); BARR();
        READ_B(1, 1); stB(0, 1, T2);
        BARR(); MFMA_Q(0, 1); BARR();
        READ_A(1, 1); stA(1, 0, T3);
        BARR(); MFMA_Q(1, 0); BARR();
        stB(1, 0, T3);
        BARR(); MFMA_Q(1, 1); VM4(); BARR();
    }

    u16* C = O0 + (size_t)kh * 4096 * 2048;
#pragma unroll
    for (int mi = 0; mi < 8; mi++)
#pragma unroll
        for (int ni = 0; ni < 4; ni++){
            int r0 = m0 + wm*128 + mi*16 + tg*4;
            int c  = n0 + wn*64 + ni*16 + lx;
#pragma unroll
            for (int j = 0; j < 4; j++)
                C[(size_t)(r0 + j) * 2048 + c] = f2bf(acc[mi][ni][j]);
        }
}

// ---------------- split-K reduce ----------------
__global__ void reduceWo(const u16* __restrict__ P, float* __restrict__ out){
    size_t t = (size_t)blockIdx.x * 256 + threadIdx.x;
    const u16* p0 = P + t * 8;
    const u16* p1 = P + 4096ull * 2048 + t * 8;
    uint4 a = *(const uint4*)p0;
    uint4 b = *(const uint4*)p1;
    const u16* as = (const u16*)&a;
    const u16* bs = (const u16*)&b;
    float4 o0, o1;
    o0.x = bf2f(as[0]) + bf2f(bs[0]); o0.y = bf2f(as[1]) + bf2f(bs[1]);
    o0.z = bf2f(as[2]) + bf2f(bs[2]); o0.w = bf2f(as[3]) + bf2f(bs[3]);
    o1.x = bf2f(as[4]) + bf2f(bs[4]); o1.y = bf2f(as[5]) + bf2f(bs[5]);
    o1.z = bf2f(as[6]) + bf2f(bs[6]); o1.w = bf2f(as[7]) + bf2f(bs[7]);
    ((float4*)out)[t * 2]     = o0;
    ((float4*)out)[t * 2 + 1] = o1;
}

// ---------------- causal GQA flash attention: swapped QK^T, in-register P ----------------
__global__ __launch_bounds__(256) void attn9(const u16* __restrict__ Q, const u16* __restrict__ Kt,
                                             const u16* __restrict__ Vt, u16* __restrict__ Y){
    __shared__ __attribute__((aligned(16))) u16 Ks[8192];
    __shared__ __attribute__((aligned(16))) u16 Vs[8192];
    const int tid = threadIdx.x;
    const int lane = tid & 63, w = tid >> 6;
    const int tg = lane >> 4, lx = lane & 15;
    int gid = blockIdx.x;
    int z = gid & 255, k4 = gid >> 8;
    int j8 = z & 7, h = (z >> 3) & 15, b = z >> 7;
    int qt = (k4 == 0) ? j8 : (k4 == 1) ? 31 - j8 : (k4 == 2) ? j8 + 8 : 23 - j8;
    const int hkv = h >> 2;
    const size_t kvBase = ((size_t)(b * NKV + hkv) * 32) * 8192;
    const f32x4 Z = {0.f, 0.f, 0.f, 0.f};

    auto STAGE_K = [&](int it){
        const u16* kg = Kt + kvBase + (size_t)it * 8192;
#pragma unroll
        for (int i = 0; i < 4; i++){
            int is = w * 4 + i;
            gld_lds16(kg + is * 512 + lane * 8, &Ks[is * 512]);
        }
    };
    auto STAGE_V = [&](int it){
        const u16* vg = Vt + kvBase + (size_t)it * 8192;
#pragma unroll
        for (int i = 0; i < 4; i++){
            int is = w * 4 + i;
            gld_lds16(vg + is * 512 + lane * 8, &Vs[is * 512]);
        }
    };

    const int q0 = qt * 64;
    const int qrow = q0 + w * 16 + lx;
    bf16x8 qfr[4];
#pragma unroll
    for (int kk = 0; kk < 4; kk++)
        qfr[kk] = *(const bf16x8*)(Q + (size_t)(b * T_ + qrow) * DM + h * HD + kk * 32 + tg * 8);
    f32x4 accO[8];
#pragma unroll
    for (int i = 0; i < 8; i++) accO[i] = Z;
    float mr = -INFINITY;
    float lp = 0.f;
    const int nIter = qt + 1;

    STAGE_K(0); STAGE_V(0);

#pragma unroll 1
    for (int it = 0; it < nIter; it++){
        const bool last = (it + 1 == nIter);
        VM4(); BARR();
        f32x4 sa[4];
#pragma unroll
        for (int c = 0; c < 4; c++) sa[c] = Z;
        __builtin_amdgcn_s_setprio(1);
#pragma unroll
        for (int c = 0; c < 4; c++){
            int s = c * 16 + lx;
            u32 swz = (u32)((s & 7) << 4);
            const char* kb = (const char*)&Ks[0] + s * 256;
#pragma unroll
            for (int kk = 0; kk < 4; kk++){
                bf16x8 kf = *(const bf16x8*)(kb + (((u32)(kk * 64 + tg * 16)) ^ swz));
                sa[c] = __builtin_amdgcn_mfma_f32_16x16x32_bf16(kf, qfr[kk], sa[c], 0, 0, 0);
            }
        }
        __builtin_amdgcn_s_setprio(0);
        BARR();
        if (!last) STAGE_K(it + 1);
        const int sBase = it * 64 + tg * 4;
        float tl = -INFINITY;
#pragma unroll
        for (int c = 0; c < 4; c++){
#pragma unroll
            for (int j = 0; j < 4; j++){
                float a = sa[c][j];
                if (last){
                    if (sBase + c * 16 + j > qrow) a = -INFINITY;
                }
                sa[c][j] = a;
                tl = fmaxf(tl, a);
            }
        }
        if (!__all(tl <= mr + 8.f)){
            float t = fmaxf(tl, __shfl_xor(tl, 16));
            t = fmaxf(t, __shfl_xor(t, 32));
            float mn = fmaxf(mr, t);
            float corrq = ex2(mr - mn);
            mr = mn;
            lp *= corrq;
            float corrO[4];
#pragma unroll
            for (int j = 0; j < 4; j++)
                corrO[j] = __shfl(corrq, (lane & 48) + ((lane >> 4) << 2) + j);
#pragma unroll
            for (int dt = 0; dt < 8; dt++){
                f32x4 t2 = accO[dt];
                t2[0] *= corrO[0]; t2[1] *= corrO[1]; t2[2] *= corrO[2]; t2[3] *= corrO[3];
                accO[dt] = t2;
            }
        }
        float p[4][4];
#pragma unroll
        for (int c = 0; c < 4; c++)
#pragma unroll
            for (int j = 0; j < 4; j++){
                float v = ex2(sa[c][j] - mr);
                p[c][j] = v;
                lp += v;
            }
        bf16x8 pa0, pa1;
        {
            u32 w0, w1, w2, w3;
            asm("v_cvt_pk_bf16_f32 %0, %1, %2" : "=v"(w0) : "v"(p[0][0]), "v"(p[0][1]));
            asm("v_cvt_pk_bf16_f32 %0, %1, %2" : "=v"(w1) : "v"(p[0][2]), "v"(p[0][3]));
            asm("v_cvt_pk_bf16_f32 %0, %1, %2" : "=v"(w2) : "v"(p[1][0]), "v"(p[1][1]));
            asm("v_cvt_pk_bf16_f32 %0, %1, %2" : "=v"(w3) : "v"(p[1][2]), "v"(p[1][3]));
            u32 r[4] = {w0, w1, w2, w3};
            pa0 = __builtin_bit_cast(bf16x8, *(uint4*)r);
            asm("v_cvt_pk_bf16_f32 %0, %1, %2" : "=v"(w0) : "v"(p[2][0]), "v"(p[2][1]));
            asm("v_cvt_pk_bf16_f32 %0, %1, %2" : "=v"(w1) : "v"(p[2][2]), "v"(p[2][3]));
            asm("v_cvt_pk_bf16_f32 %0, %1, %2" : "=v"(w2) : "v"(p[3][0]), "v"(p[3][1]));
            asm("v_cvt_pk_bf16_f32 %0, %1, %2" : "=v"(w3) : "v"(p[3][2]), "v"(p[3][3]));
            u32 r2[4] = {w0, w1, w2, w3};
            pa1 = __builtin_bit_cast(bf16x8, *(uint4*)r2);
        }
        if (last){ VM0(); } else { VM4(); }
        BARR();
        __builtin_amdgcn_s_setprio(1);
#pragma unroll
        for (int dt = 0; dt < 8; dt++){
            int d = dt * 16 + lx;
            u32 swz = (u32)((d & 7) << 4);
            const char* vb = (const char*)&Vs[0] + d * 128;
            bf16x8 vf0 = *(const bf16x8*)(vb + (((u32)(tg * 16))      ^ swz));
            bf16x8 vf1 = *(const bf16x8*)(vb + (((u32)(tg * 16 + 64)) ^ swz));
            accO[dt] = __builtin_amdgcn_mfma_f32_16x16x32_bf16(pa0, vf0, accO[dt], 0, 0, 0);
            accO[dt] = __builtin_amdgcn_mfma_f32_16x16x32_bf16(pa1, vf1, accO[dt], 0, 0, 0);
        }
        __builtin_amdgcn_s_setprio(0);
        BARR();
        if (!last) STAGE_V(it + 1);
    }
    lp += __shfl_xor(lp, 16);
    lp += __shfl_xor(lp, 32);
    float invq = 1.0f / lp;
    float inv[4];
#pragma unroll
    for (int j = 0; j < 4; j++)
        inv[j] = __shfl(invq, (lane & 48) + ((lane >> 4) << 2) + j);
#pragma unroll
    for (int dt = 0; dt < 8; dt++)
#pragma unroll
        for (int j = 0; j < 4; j++){
            int qr = q0 + w * 16 + tg * 4 + j;
            int d = dt * 16 + lx;
            Y[(size_t)(b * T_ + qr) * DM + h * HD + d] = f2bf(accO[dt][j] * inv[j]);
        }
}

extern "C" void kernel_launch(void* const* d_in, const int* in_sizes, int n_in,
                              void* d_out, int out_size, void* d_ws, size_t ws_size,
                              hipStream_t stream){
    const float* x  = (const float*)d_in[0];
    const float* Wq = (const float*)d_in[1];
    const float* Wk = (const float*)d_in[2];
    const float* Wv = (const float*)d_in[3];
    const float* Wo = (const float*)d_in[4];

    char* ws = (char*)d_ws;
    size_t off = 0;
    auto alloc = [&](size_t bytes){ void* p = ws + off; off += (bytes + 255) & ~255ull; return p; };
    u16*    xb   = (u16*)alloc(4096ull * 2048 * 2);
    u16*    Wqkv = (u16*)alloc(3072ull * 2048 * 2);
    u16*    Wot  = (u16*)alloc(2048ull * 2048 * 2);
    u16*    qbb  = (u16*)alloc(4096ull * 2048 * 2);
    u16*    ktl  = (u16*)alloc(2ull * 4 * 32 * 8192 * 2);
    u16*    vtl  = (u16*)alloc(2ull * 4 * 32 * 8192 * 2);
    u16*    ybb  = (u16*)alloc(4096ull * 2048 * 2);
    u16*    pbb  = (u16*)alloc(2ull * 4096 * 2048 * 2);
    float2* tab  = (float2*)alloc(2048ull * 64 * 8);

    prep<<<18944, 256, 0, stream>>>(x, Wq, Wk, Wv, Wo, xb, Wqkv, Wot, tab);

    gemm192h<<<512, 256, 0, stream>>>(xb, Wqkv, qbb, ktl, vtl, tab);

    attn9<<<1024, 256, 0, stream>>>(qbb, ktl, vtl, ybb);

    gemmWo<<<256, 512, 0, stream>>>(ybb, Wot, pbb);
    reduceWo<<<4096, 256, 0, stream>>>(pbb, (float*)d_out);
}